// Round 2
// baseline (1908.535 us; speedup 1.0000x reference)
//
#include <hip/hip_runtime.h>
#include <cstdint>
#include <cstddef>

// Shapes (fixed by the problem)
#define NTOK 8192   // B*T
#define CDIM 1024
#define HDIM 2048
#define NEXP 8

typedef __bf16 bf16;
typedef unsigned short u16;
typedef __attribute__((ext_vector_type(8))) __bf16 bf16x8;
typedef __attribute__((ext_vector_type(4))) __bf16 bf16x4;
typedef __attribute__((ext_vector_type(4))) float f32x4;

__device__ __forceinline__ u16 f2bf(float f) {
  union { u16 u; __bf16 b; } cv;
  cv.b = (__bf16)f;
  return cv.u;
}

// Async global->LDS, 16B per lane (lane-linear LDS dest).
__device__ __forceinline__ void gload_lds16(const bf16* g, bf16* l) {
  __builtin_amdgcn_global_load_lds(
      (const __attribute__((address_space(1))) unsigned int*)g,
      (__attribute__((address_space(3))) unsigned int*)l, 16, 0, 0);
}

// ---------------- x: fp32 -> bf16 ----------------
__global__ __launch_bounds__(256) void cast_x_kernel(
    const float* __restrict__ src, bf16* __restrict__ dst) {
  size_t i = ((size_t)blockIdx.x * 256 + threadIdx.x) * 8;
  float4 a = *(const float4*)(src + i);
  float4 b = *(const float4*)(src + i + 4);
  bf16x8 p;
  p[0] = (bf16)a.x; p[1] = (bf16)a.y; p[2] = (bf16)a.z; p[3] = (bf16)a.w;
  p[4] = (bf16)b.x; p[5] = (bf16)b.y; p[6] = (bf16)b.z; p[7] = (bf16)b.w;
  *(bf16x8*)(dst + i) = p;
}

// ---------------- router: logits, top-2 softmax -> dense per-expert weights ----------------
__global__ __launch_bounds__(256) void router_kernel(
    const float* __restrict__ x, const float* __restrict__ gw,
    float* __restrict__ dense_w, float* __restrict__ logits_out) {
  int wv = threadIdx.x >> 6, l = threadIdx.x & 63;
  int t = blockIdx.x * 4 + wv;
  const float* xr = x + (size_t)t * CDIM;
  float acc[NEXP];
#pragma unroll
  for (int e = 0; e < NEXP; ++e) acc[e] = 0.f;
  for (int c = l; c < CDIM; c += 64) {
    float xv = xr[c];
    const float* g = gw + (size_t)c * NEXP;
    float4 g0 = *(const float4*)(g);
    float4 g1 = *(const float4*)(g + 4);
    acc[0] += xv * g0.x; acc[1] += xv * g0.y; acc[2] += xv * g0.z; acc[3] += xv * g0.w;
    acc[4] += xv * g1.x; acc[5] += xv * g1.y; acc[6] += xv * g1.z; acc[7] += xv * g1.w;
  }
#pragma unroll
  for (int off = 32; off > 0; off >>= 1) {
#pragma unroll
    for (int e = 0; e < NEXP; ++e) acc[e] += __shfl_xor(acc[e], off, 64);
  }
  // top-2; ties pick lower index (matches jax top_k)
  int e0 = 0; float l0 = acc[0];
#pragma unroll
  for (int e = 1; e < NEXP; ++e) { if (acc[e] > l0) { l0 = acc[e]; e0 = e; } }
  int e1 = -1; float l1 = -3.4e38f;
#pragma unroll
  for (int e = 0; e < NEXP; ++e) { if (e != e0 && acc[e] > l1) { l1 = acc[e]; e1 = e; } }
  float ex = expf(l1 - l0);
  float w0 = 1.f / (1.f + ex), w1 = ex / (1.f + ex);
  if (l < NEXP) {
    dense_w[(size_t)t * NEXP + l] = (l == e0) ? w0 : ((l == e1) ? w1 : 0.f);
    logits_out[(size_t)t * NEXP + l] = acc[l];
  }
}

// ---------------- transpose+cast: fp32 RxC -> bf16 CxR (dims multiples of 64) ----------------
__global__ __launch_bounds__(256) void transpose_cast_kernel(
    const float* __restrict__ src, u16* __restrict__ dst, int R, int C) {
  __shared__ u16 tile[64][65];
  int r0 = blockIdx.y * 64, c0 = blockIdx.x * 64;
  int tr = threadIdx.x >> 2;          // [0,64)
  int tc = (threadIdx.x & 3) * 16;    // {0,16,32,48}
  const float* s = src + (size_t)(r0 + tr) * C + c0 + tc;
  float4 f[4];
#pragma unroll
  for (int q = 0; q < 4; ++q) f[q] = *(const float4*)(s + q * 4);
#pragma unroll
  for (int q = 0; q < 4; ++q) {
    tile[tr][tc + q * 4 + 0] = f2bf(f[q].x);
    tile[tr][tc + q * 4 + 1] = f2bf(f[q].y);
    tile[tr][tc + q * 4 + 2] = f2bf(f[q].z);
    tile[tr][tc + q * 4 + 3] = f2bf(f[q].w);
  }
  __syncthreads();
  union { uint4 v[2]; u16 e[16]; } u;
#pragma unroll
  for (int j = 0; j < 16; ++j) u.e[j] = tile[tc + j][tr];
  u16* d = dst + (size_t)(c0 + tr) * R + r0 + tc;
  *(uint4*)d = u.v[0];
  *(uint4*)(d + 8) = u.v[1];
}

// ---------------- GEMM: D(MxN) = A(MxK) * Bt(NxK)^T, m97 structure ----------------
// MODE 0: store bf16 D
// MODE 1: store bf16 silu(G)*D   (G read from Gin; in-place over Gin is safe)
// MODE 2: outAcc = D             (f32, shared expert, initializes)
// MODE 3: outAcc += w[m]*D       (f32, routed expert, dense router weight)
template <int MODE>
__global__ __launch_bounds__(256) void gemm_bt(
    const bf16* __restrict__ A, const bf16* __restrict__ Bt,
    int K, int N,
    bf16* __restrict__ Dbf, const bf16* __restrict__ Gin,
    float* __restrict__ outAcc, const float* __restrict__ denseW, int expertId) {
  __shared__ __align__(16) bf16 sA[128 * 32];
  __shared__ __align__(16) bf16 sB[128 * 32];
  const int tid = threadIdx.x;
  const int l = tid & 63, wv = tid >> 6;
  const int wr = wv >> 1, wc = wv & 1;
  const int m0 = blockIdx.y * 128, n0 = blockIdx.x * 128;

  f32x4 acc[4][4];
#pragma unroll
  for (int i = 0; i < 4; ++i)
#pragma unroll
    for (int j = 0; j < 4; ++j) acc[i][j] = (f32x4){0.f, 0.f, 0.f, 0.f};

  // staging: 256 threads x 16B covers 64 rows x 32 cols; two issues = 128 rows
  const int srow = wv * 16 + (l >> 2);
  const int scol = (l & 3) * 8;
  const bf16* gA = A + (size_t)(m0 + srow) * K + scol;
  const bf16* gB = Bt + (size_t)(n0 + srow) * K + scol;
  bf16* lA = sA + srow * 32 + scol;  // lane-linear: byte off = wv*1024 + l*16
  bf16* lB = sB + srow * 32 + scol;

  const int fr = l & 15, fk = (l >> 4) * 8;
  const bf16* rA = sA + (size_t)(wr * 64 + fr) * 32 + fk;
  const bf16* rB = sB + (size_t)(wc * 64 + fr) * 32 + fk;

  for (int k0 = 0; k0 < K; k0 += 32) {
    __syncthreads();
    gload_lds16(gA, lA);
    gload_lds16(gA + (size_t)64 * K, lA + 64 * 32);
    gload_lds16(gB, lB);
    gload_lds16(gB + (size_t)64 * K, lB + 64 * 32);
    gA += 32; gB += 32;
    __syncthreads();  // drains vmcnt -> LDS data visible
    bf16x8 af[4], bfr[4];
#pragma unroll
    for (int i = 0; i < 4; ++i) af[i] = *(const bf16x8*)(rA + i * 16 * 32);
#pragma unroll
    for (int j = 0; j < 4; ++j) bfr[j] = *(const bf16x8*)(rB + j * 16 * 32);
#pragma unroll
    for (int i = 0; i < 4; ++i)
#pragma unroll
      for (int j = 0; j < 4; ++j)
        acc[i][j] = __builtin_amdgcn_mfma_f32_16x16x32_bf16(af[i], bfr[j], acc[i][j], 0, 0, 0);
  }

  // C/D layout: col = lane&15, row = (lane>>4)*4 + reg
  const int cn = n0 + wc * 64 + (l & 15);
  const int rb = m0 + wr * 64 + (l >> 4) * 4;
#pragma unroll
  for (int i = 0; i < 4; ++i) {
#pragma unroll
    for (int r = 0; r < 4; ++r) {
      const int m = rb + i * 16 + r;
#pragma unroll
      for (int j = 0; j < 4; ++j) {
        const int n = cn + j * 16;
        float v = acc[i][j][r];
        if (MODE == 0) {
          Dbf[(size_t)m * N + n] = (bf16)v;
        } else if (MODE == 1) {
          float g = (float)Gin[(size_t)m * N + n];
          float s = g / (1.f + expf(-g));
          Dbf[(size_t)m * N + n] = (bf16)(s * v);
        } else if (MODE == 2) {
          outAcc[(size_t)m * N + n] = v;
        } else {
          float w = denseW[(size_t)m * NEXP + expertId];
          outAcc[(size_t)m * N + n] += w * v;
        }
      }
    }
  }
}

extern "C" void kernel_launch(void* const* d_in, const int* in_sizes, int n_in,
                              void* d_out, int out_size, void* d_ws, size_t ws_size,
                              hipStream_t stream) {
  const float* x    = (const float*)d_in[0];
  const float* gate = (const float*)d_in[1];
  const float* sg   = (const float*)d_in[2];
  const float* su   = (const float*)d_in[3];
  const float* sd   = (const float*)d_in[4];
  const float* eg   = (const float*)d_in[5];
  const float* eu   = (const float*)d_in[6];
  const float* ed   = (const float*)d_in[7];
  float* out    = (float*)d_out;                 // 8192x1024 fp32 (accumulated in place)
  float* logits = out + (size_t)NTOK * CDIM;     // 8192x8 fp32

  // ws layout (~60.3 MB)
  char* ws = (char*)d_ws;
  bf16*  xb   = (bf16*)(ws);                        // 8192x1024 bf16, 16 MB
  bf16*  wTg  = (bf16*)(ws + (16u << 20));          // HxC bf16, 4 MB (reused per expert)
  bf16*  wTu  = (bf16*)(ws + (20u << 20));          // HxC bf16, 4 MB
  bf16*  wTd  = (bf16*)(ws + (24u << 20));          // CxH bf16, 4 MB
  bf16*  gbuf = (bf16*)(ws + (28u << 20));          // 8192x2048 bf16, 32 MB
  float* dw   = (float*)(ws + (60u << 20));         // 8192x8 f32, 256 KB
  if (ws_size < (size_t)(60u << 20) + (size_t)NTOK * NEXP * sizeof(float)) return;

  cast_x_kernel<<<(NTOK * CDIM) / (256 * 8), 256, 0, stream>>>(x, xb);
  router_kernel<<<NTOK / 4, 256, 0, stream>>>(x, gate, dw, logits);

  dim3 tg1(HDIM / 64, CDIM / 64);   // transpose CxH -> HxC
  dim3 tg2(CDIM / 64, HDIM / 64);   // transpose HxC -> CxH
  dim3 g1(HDIM / 128, NTOK / 128);  // gemm1: N=H
  dim3 g2(CDIM / 128, NTOK / 128);  // gemm2: N=C

  // shared expert
  transpose_cast_kernel<<<tg1, 256, 0, stream>>>(sg, (u16*)wTg, CDIM, HDIM);
  transpose_cast_kernel<<<tg1, 256, 0, stream>>>(su, (u16*)wTu, CDIM, HDIM);
  transpose_cast_kernel<<<tg2, 256, 0, stream>>>(sd, (u16*)wTd, HDIM, CDIM);
  gemm_bt<0><<<g1, 256, 0, stream>>>(xb, wTg, CDIM, HDIM, gbuf, nullptr, nullptr, nullptr, 0);
  gemm_bt<1><<<g1, 256, 0, stream>>>(xb, wTu, CDIM, HDIM, gbuf, gbuf, nullptr, nullptr, 0);
  gemm_bt<2><<<g2, 256, 0, stream>>>(gbuf, wTd, HDIM, CDIM, nullptr, nullptr, out, nullptr, 0);

  // routed experts (dense: all tokens computed, weight folded via scale; w=0 rows no-op)
  for (int e = 0; e < NEXP; ++e) {
    const float* egp = eg + (size_t)e * CDIM * HDIM;
    const float* eup = eu + (size_t)e * CDIM * HDIM;
    const float* edp = ed + (size_t)e * HDIM * CDIM;
    transpose_cast_kernel<<<tg1, 256, 0, stream>>>(egp, (u16*)wTg, CDIM, HDIM);
    transpose_cast_kernel<<<tg1, 256, 0, stream>>>(eup, (u16*)wTu, CDIM, HDIM);
    transpose_cast_kernel<<<tg2, 256, 0, stream>>>(edp, (u16*)wTd, HDIM, CDIM);
    gemm_bt<0><<<g1, 256, 0, stream>>>(xb, wTg, CDIM, HDIM, gbuf, nullptr, nullptr, nullptr, 0);
    gemm_bt<1><<<g1, 256, 0, stream>>>(xb, wTu, CDIM, HDIM, gbuf, gbuf, nullptr, nullptr, 0);
    gemm_bt<3><<<g2, 256, 0, stream>>>(gbuf, wTd, HDIM, CDIM, nullptr, nullptr, out, dw, e);
  }
}

// Round 3
// 1254.711 us; speedup vs baseline: 1.5211x; 1.5211x over previous
//
#include <hip/hip_runtime.h>
#include <cstdint>
#include <cstddef>

// Shapes (fixed by the problem)
#define NTOK 8192   // B*T
#define CDIM 1024
#define HDIM 2048
#define NEXP 8
#define NSEG 9        // 8 routed + 1 shared
#define MAXTILES 200  // worst case: 135 routed tiles + 64 shared + slack
#define MAXROWS (MAXTILES * 128)

typedef __bf16 bf16;
typedef unsigned short u16;
typedef __attribute__((ext_vector_type(8))) __bf16 bf16x8;
typedef __attribute__((ext_vector_type(4))) float f32x4;

__device__ __forceinline__ u16 f2bf(float f) {
  union { u16 u; __bf16 b; } cv;
  cv.b = (__bf16)f;
  return cv.u;
}

// Async global->LDS, 16B per lane. Global address may be per-lane arbitrary;
// only the LDS dest must be wave-uniform base + lane*16 (ours is lane-linear).
__device__ __forceinline__ void gload_lds16(const bf16* g, bf16* l) {
  __builtin_amdgcn_global_load_lds(
      (const __attribute__((address_space(1))) unsigned int*)g,
      (__attribute__((address_space(3))) unsigned int*)l, 16, 0, 0);
}

// ---------------- zero out + control counters ----------------
__global__ __launch_bounds__(256) void zero_kernel(float* __restrict__ out,
                                                   int* __restrict__ counts,
                                                   int* __restrict__ fill) {
  size_t i = ((size_t)blockIdx.x * 256 + threadIdx.x) * 4;
  if (i < (size_t)NTOK * CDIM) {
    float4 z = {0.f, 0.f, 0.f, 0.f};
    *(float4*)(out + i) = z;
  }
  if (blockIdx.x == 0 && threadIdx.x < NEXP) {
    counts[threadIdx.x] = 0;
    fill[threadIdx.x] = 0;
  }
}

// ---------------- x: fp32 -> bf16 ----------------
__global__ __launch_bounds__(256) void cast_x_kernel(
    const float* __restrict__ src, bf16* __restrict__ dst) {
  size_t i = ((size_t)blockIdx.x * 256 + threadIdx.x) * 8;
  float4 a = *(const float4*)(src + i);
  float4 b = *(const float4*)(src + i + 4);
  bf16x8 p;
  p[0] = (bf16)a.x; p[1] = (bf16)a.y; p[2] = (bf16)a.z; p[3] = (bf16)a.w;
  p[4] = (bf16)b.x; p[5] = (bf16)b.y; p[6] = (bf16)b.z; p[7] = (bf16)b.w;
  *(bf16x8*)(dst + i) = p;
}

// ---------------- router (new path): logits + top2 + per-expert counts ----------------
__global__ __launch_bounds__(256) void router2_kernel(
    const float* __restrict__ x, const float* __restrict__ gw,
    float* __restrict__ logits_out, int* __restrict__ tk_e,
    float* __restrict__ tk_w, int* __restrict__ counts) {
  int wv = threadIdx.x >> 6, l = threadIdx.x & 63;
  int t = blockIdx.x * 4 + wv;
  const float* xr = x + (size_t)t * CDIM;
  float acc[NEXP];
#pragma unroll
  for (int e = 0; e < NEXP; ++e) acc[e] = 0.f;
  for (int c = l; c < CDIM; c += 64) {
    float xv = xr[c];
    const float* g = gw + (size_t)c * NEXP;
    float4 g0 = *(const float4*)(g);
    float4 g1 = *(const float4*)(g + 4);
    acc[0] += xv * g0.x; acc[1] += xv * g0.y; acc[2] += xv * g0.z; acc[3] += xv * g0.w;
    acc[4] += xv * g1.x; acc[5] += xv * g1.y; acc[6] += xv * g1.z; acc[7] += xv * g1.w;
  }
#pragma unroll
  for (int off = 32; off > 0; off >>= 1) {
#pragma unroll
    for (int e = 0; e < NEXP; ++e) acc[e] += __shfl_xor(acc[e], off, 64);
  }
  int e0 = 0; float l0 = acc[0];
#pragma unroll
  for (int e = 1; e < NEXP; ++e) { if (acc[e] > l0) { l0 = acc[e]; e0 = e; } }
  int e1 = -1; float l1 = -3.4e38f;
#pragma unroll
  for (int e = 0; e < NEXP; ++e) { if (e != e0 && acc[e] > l1) { l1 = acc[e]; e1 = e; } }
  float ex = expf(l1 - l0);
  float w0 = 1.f / (1.f + ex), w1 = ex / (1.f + ex);
  if (l < NEXP) logits_out[(size_t)t * NEXP + l] = acc[l];
  if (l == 0) {
    tk_e[2 * t] = e0; tk_e[2 * t + 1] = e1;
    tk_w[2 * t] = w0; tk_w[2 * t + 1] = w1;
    atomicAdd(&counts[e0], 1);
    atomicAdd(&counts[e1], 1);
  }
}

// ---------------- segment offsets, tile->segment map, pad fill ----------------
__global__ __launch_bounds__(256) void offsets_kernel(
    const int* __restrict__ counts, int* __restrict__ offs_g,
    int* __restrict__ tile_seg, int* __restrict__ list_tok,
    float* __restrict__ list_w) {
  __shared__ int off[NSEG], pad[NSEG], cnt[NSEG], ntot;
  int tid = threadIdx.x;
  if (tid == 0) {
    int tot = 0;
    for (int e = 0; e < NSEG; ++e) {
      int c = (e < NEXP) ? counts[e] : NTOK;
      cnt[e] = c; off[e] = tot;
      int p = (c + 127) & ~127;
      pad[e] = p; tot += p;
    }
    ntot = tot;
  }
  __syncthreads();
  if (tid < NSEG) offs_g[tid] = off[tid];
  for (int gt = tid; gt < MAXTILES; gt += 256) {
    int row = gt * 128, seg = -1;
    if (row < ntot) {
      for (int e = 0; e < NSEG; ++e)
        if (row >= off[e] && row < off[e] + pad[e]) { seg = e; break; }
    }
    tile_seg[gt] = seg;
  }
  for (int e = 0; e < NSEG; ++e)
    for (int i = off[e] + cnt[e] + tid; i < off[e] + pad[e]; i += 256) {
      list_tok[i] = 0; list_w[i] = 0.f;
    }
}

// ---------------- scatter tokens into compact per-expert lists ----------------
__global__ __launch_bounds__(256) void scatter_kernel(
    const int* __restrict__ tk_e, const float* __restrict__ tk_w,
    const int* __restrict__ offs, int* __restrict__ fill,
    int* __restrict__ list_tok, float* __restrict__ list_w) {
  int t = blockIdx.x * 256 + threadIdx.x;
  int e0 = tk_e[2 * t], e1 = tk_e[2 * t + 1];
  float w0 = tk_w[2 * t], w1 = tk_w[2 * t + 1];
  int p0 = atomicAdd(&fill[e0], 1);
  int i0 = offs[e0] + p0;
  list_tok[i0] = t; list_w[i0] = w0;
  int p1 = atomicAdd(&fill[e1], 1);
  int i1 = offs[e1] + p1;
  list_tok[i1] = t; list_w[i1] = w1;
  int i2 = offs[NEXP] + t;  // shared segment: identity, weight 1
  list_tok[i2] = t; list_w[i2] = 1.f;
}

// ---------------- transpose+cast body: fp32 RxC -> bf16 CxR ----------------
__device__ __forceinline__ void transpose_body(const float* __restrict__ src,
                                               u16* __restrict__ dst, int R, int C) {
  __shared__ u16 tile[64][65];
  int r0 = blockIdx.y * 64, c0 = blockIdx.x * 64;
  int tr = threadIdx.x >> 2;
  int tc = (threadIdx.x & 3) * 16;
  const float* s = src + (size_t)(r0 + tr) * C + c0 + tc;
  float4 f[4];
#pragma unroll
  for (int q = 0; q < 4; ++q) f[q] = *(const float4*)(s + q * 4);
#pragma unroll
  for (int q = 0; q < 4; ++q) {
    tile[tr][tc + q * 4 + 0] = f2bf(f[q].x);
    tile[tr][tc + q * 4 + 1] = f2bf(f[q].y);
    tile[tr][tc + q * 4 + 2] = f2bf(f[q].z);
    tile[tr][tc + q * 4 + 3] = f2bf(f[q].w);
  }
  __syncthreads();
  union { uint4 v[2]; u16 e[16]; } u;
#pragma unroll
  for (int j = 0; j < 16; ++j) u.e[j] = tile[tc + j][tr];
  u16* d = dst + (size_t)(c0 + tr) * R + r0 + tc;
  *(uint4*)d = u.v[0];
  *(uint4*)(d + 8) = u.v[1];
}

__global__ __launch_bounds__(256) void transpose_cast_kernel(
    const float* __restrict__ src, u16* __restrict__ dst, int R, int C) {
  transpose_body(src, dst, R, C);
}

// gate/up weights: (C,H) -> (H,C). z: 0=sg,1=su, 2..9=eg[e], 10..17=eu[e]
__global__ __launch_bounds__(256) void transpose_gu_kernel(
    const float* __restrict__ sg, const float* __restrict__ su,
    const float* __restrict__ eg, const float* __restrict__ eu,
    u16* __restrict__ wTg, u16* __restrict__ wTu) {
  const size_t slot = (size_t)HDIM * CDIM;
  int z = blockIdx.z;
  const float* src; u16* dst;
  if (z == 0)       { src = sg;                 dst = wTg + 8 * slot; }
  else if (z == 1)  { src = su;                 dst = wTu + 8 * slot; }
  else if (z < 10)  { src = eg + (z - 2) * slot;  dst = wTg + (z - 2) * slot; }
  else              { src = eu + (z - 10) * slot; dst = wTu + (z - 10) * slot; }
  transpose_body(src, dst, CDIM, HDIM);
}

// down weights: (H,C) -> (C,H). z: 0=sd, 1..8=ed[e]
__global__ __launch_bounds__(256) void transpose_d_kernel(
    const float* __restrict__ sd, const float* __restrict__ ed,
    u16* __restrict__ wTd) {
  const size_t slot = (size_t)HDIM * CDIM;
  int z = blockIdx.z;
  const float* src; u16* dst;
  if (z == 0) { src = sd;                 dst = wTd + 8 * slot; }
  else        { src = ed + (z - 1) * slot; dst = wTd + (z - 1) * slot; }
  transpose_body(src, dst, HDIM, CDIM);
}

// ---------------- fused gate+up gather-GEMM with silu epilogue ----------------
// act[row, n] = silu(x[tok]@Wg[seg])[n] * (x[tok]@Wu[seg])[n]
__global__ __launch_bounds__(256) void gemm_gu(
    const bf16* __restrict__ xb, const bf16* __restrict__ wTg,
    const bf16* __restrict__ wTu, const int* __restrict__ tile_seg,
    const int* __restrict__ list_tok, bf16* __restrict__ act) {
  __shared__ __align__(16) bf16 sA[128 * 32];
  __shared__ __align__(16) bf16 sBg[128 * 32];
  __shared__ __align__(16) bf16 sBu[128 * 32];
  __shared__ int tokLds[128];
  const int seg = tile_seg[blockIdx.y];
  if (seg < 0) return;
  const int tid = threadIdx.x, l = tid & 63, wv = tid >> 6;
  const int wr = wv >> 1, wc = wv & 1;
  const int n0 = blockIdx.x * 128;
  const size_t rowbase = (size_t)blockIdx.y * 128;
  if (tid < 128) tokLds[tid] = list_tok[rowbase + tid];
  __syncthreads();

  f32x4 accG[4][4], accU[4][4];
#pragma unroll
  for (int i = 0; i < 4; ++i)
#pragma unroll
    for (int j = 0; j < 4; ++j) {
      accG[i][j] = (f32x4){0.f, 0.f, 0.f, 0.f};
      accU[i][j] = (f32x4){0.f, 0.f, 0.f, 0.f};
    }

  const int srow = wv * 16 + (l >> 2);
  const int scol = (l & 3) * 8;
  const bf16* gA  = xb + (size_t)tokLds[srow] * CDIM + scol;
  const bf16* gA2 = xb + (size_t)tokLds[srow + 64] * CDIM + scol;
  const size_t wslot = (size_t)seg * HDIM * CDIM;
  const bf16* gBg = wTg + wslot + (size_t)(n0 + srow) * CDIM + scol;
  const bf16* gBu = wTu + wslot + (size_t)(n0 + srow) * CDIM + scol;
  bf16* lA  = sA  + srow * 32 + scol;
  bf16* lBg = sBg + srow * 32 + scol;
  bf16* lBu = sBu + srow * 32 + scol;

  const int fr = l & 15, fk = (l >> 4) * 8;
  const bf16* rA  = sA  + (size_t)(wr * 64 + fr) * 32 + fk;
  const bf16* rBg = sBg + (size_t)(wc * 64 + fr) * 32 + fk;
  const bf16* rBu = sBu + (size_t)(wc * 64 + fr) * 32 + fk;

  for (int k0 = 0; k0 < CDIM; k0 += 32) {
    __syncthreads();
    gload_lds16(gA, lA);
    gload_lds16(gA2, lA + 64 * 32);
    gload_lds16(gBg, lBg);
    gload_lds16(gBg + (size_t)64 * CDIM, lBg + 64 * 32);
    gload_lds16(gBu, lBu);
    gload_lds16(gBu + (size_t)64 * CDIM, lBu + 64 * 32);
    gA += 32; gA2 += 32; gBg += 32; gBu += 32;
    __syncthreads();
    bf16x8 af[4], bg[4], bu[4];
#pragma unroll
    for (int i = 0; i < 4; ++i) af[i] = *(const bf16x8*)(rA + i * 16 * 32);
#pragma unroll
    for (int j = 0; j < 4; ++j) bg[j] = *(const bf16x8*)(rBg + j * 16 * 32);
#pragma unroll
    for (int j = 0; j < 4; ++j) bu[j] = *(const bf16x8*)(rBu + j * 16 * 32);
#pragma unroll
    for (int i = 0; i < 4; ++i)
#pragma unroll
      for (int j = 0; j < 4; ++j) {
        accG[i][j] = __builtin_amdgcn_mfma_f32_16x16x32_bf16(af[i], bg[j], accG[i][j], 0, 0, 0);
        accU[i][j] = __builtin_amdgcn_mfma_f32_16x16x32_bf16(af[i], bu[j], accU[i][j], 0, 0, 0);
      }
  }

  const int cn = n0 + wc * 64 + (l & 15);
  const int rb = wr * 64 + (l >> 4) * 4;
#pragma unroll
  for (int i = 0; i < 4; ++i)
#pragma unroll
    for (int r = 0; r < 4; ++r) {
      const size_t row = rowbase + rb + i * 16 + r;
#pragma unroll
      for (int j = 0; j < 4; ++j) {
        float g = accG[i][j][r], u = accU[i][j][r];
        float s = g / (1.f + expf(-g));
        act[row * HDIM + cn + j * 16] = (bf16)(s * u);
      }
    }
}

// ---------------- down-proj GEMM with weighted scatter-atomic epilogue ----------------
__global__ __launch_bounds__(256) void gemm_down(
    const bf16* __restrict__ act, const bf16* __restrict__ wTd,
    const int* __restrict__ tile_seg, const int* __restrict__ list_tok,
    const float* __restrict__ list_w, float* __restrict__ out) {
  __shared__ __align__(16) bf16 sA[128 * 32];
  __shared__ __align__(16) bf16 sB[128 * 32];
  __shared__ int tokLds[128];
  __shared__ float wLds[128];
  const int seg = tile_seg[blockIdx.y];
  if (seg < 0) return;
  const int tid = threadIdx.x, l = tid & 63, wv = tid >> 6;
  const int wr = wv >> 1, wc = wv & 1;
  const int n0 = blockIdx.x * 128;
  const size_t rowbase = (size_t)blockIdx.y * 128;
  if (tid < 128) {
    tokLds[tid] = list_tok[rowbase + tid];
    wLds[tid] = list_w[rowbase + tid];
  }

  f32x4 acc[4][4];
#pragma unroll
  for (int i = 0; i < 4; ++i)
#pragma unroll
    for (int j = 0; j < 4; ++j) acc[i][j] = (f32x4){0.f, 0.f, 0.f, 0.f};

  const int srow = wv * 16 + (l >> 2);
  const int scol = (l & 3) * 8;
  const bf16* gA = act + (rowbase + srow) * HDIM + scol;
  const bf16* gB = wTd + (size_t)seg * CDIM * HDIM + (size_t)(n0 + srow) * HDIM + scol;
  bf16* lA = sA + srow * 32 + scol;
  bf16* lB = sB + srow * 32 + scol;

  const int fr = l & 15, fk = (l >> 4) * 8;
  const bf16* rA = sA + (size_t)(wr * 64 + fr) * 32 + fk;
  const bf16* rB = sB + (size_t)(wc * 64 + fr) * 32 + fk;

  for (int k0 = 0; k0 < HDIM; k0 += 32) {
    __syncthreads();
    gload_lds16(gA, lA);
    gload_lds16(gA + (size_t)64 * HDIM, lA + 64 * 32);
    gload_lds16(gB, lB);
    gload_lds16(gB + (size_t)64 * HDIM, lB + 64 * 32);
    gA += 32; gB += 32;
    __syncthreads();
    bf16x8 af[4], bf[4];
#pragma unroll
    for (int i = 0; i < 4; ++i) af[i] = *(const bf16x8*)(rA + i * 16 * 32);
#pragma unroll
    for (int j = 0; j < 4; ++j) bf[j] = *(const bf16x8*)(rB + j * 16 * 32);
#pragma unroll
    for (int i = 0; i < 4; ++i)
#pragma unroll
      for (int j = 0; j < 4; ++j)
        acc[i][j] = __builtin_amdgcn_mfma_f32_16x16x32_bf16(af[i], bf[j], acc[i][j], 0, 0, 0);
  }

  const int cn = n0 + wc * 64 + (l & 15);
  const int rb = wr * 64 + (l >> 4) * 4;
#pragma unroll
  for (int i = 0; i < 4; ++i)
#pragma unroll
    for (int r = 0; r < 4; ++r) {
      const int m = rb + i * 16 + r;
      const int tok = tokLds[m];
      const float w = wLds[m];
#pragma unroll
      for (int j = 0; j < 4; ++j)
        atomicAdd(&out[(size_t)tok * CDIM + cn + j * 16], w * acc[i][j][r]);
    }
}

// ================= FALLBACK (round-2 dense path) =================
__global__ __launch_bounds__(256) void router_kernel(
    const float* __restrict__ x, const float* __restrict__ gw,
    float* __restrict__ dense_w, float* __restrict__ logits_out) {
  int wv = threadIdx.x >> 6, l = threadIdx.x & 63;
  int t = blockIdx.x * 4 + wv;
  const float* xr = x + (size_t)t * CDIM;
  float acc[NEXP];
#pragma unroll
  for (int e = 0; e < NEXP; ++e) acc[e] = 0.f;
  for (int c = l; c < CDIM; c += 64) {
    float xv = xr[c];
    const float* g = gw + (size_t)c * NEXP;
    float4 g0 = *(const float4*)(g);
    float4 g1 = *(const float4*)(g + 4);
    acc[0] += xv * g0.x; acc[1] += xv * g0.y; acc[2] += xv * g0.z; acc[3] += xv * g0.w;
    acc[4] += xv * g1.x; acc[5] += xv * g1.y; acc[6] += xv * g1.z; acc[7] += xv * g1.w;
  }
#pragma unroll
  for (int off = 32; off > 0; off >>= 1) {
#pragma unroll
    for (int e = 0; e < NEXP; ++e) acc[e] += __shfl_xor(acc[e], off, 64);
  }
  int e0 = 0; float l0 = acc[0];
#pragma unroll
  for (int e = 1; e < NEXP; ++e) { if (acc[e] > l0) { l0 = acc[e]; e0 = e; } }
  int e1 = -1; float l1 = -3.4e38f;
#pragma unroll
  for (int e = 0; e < NEXP; ++e) { if (e != e0 && acc[e] > l1) { l1 = acc[e]; e1 = e; } }
  float ex = expf(l1 - l0);
  float w0 = 1.f / (1.f + ex), w1 = ex / (1.f + ex);
  if (l < NEXP) {
    dense_w[(size_t)t * NEXP + l] = (l == e0) ? w0 : ((l == e1) ? w1 : 0.f);
    logits_out[(size_t)t * NEXP + l] = acc[l];
  }
}

template <int MODE>
__global__ __launch_bounds__(256) void gemm_bt(
    const bf16* __restrict__ A, const bf16* __restrict__ Bt,
    int K, int N,
    bf16* __restrict__ Dbf, const bf16* __restrict__ Gin,
    float* __restrict__ outAcc, const float* __restrict__ denseW, int expertId) {
  __shared__ __align__(16) bf16 sA[128 * 32];
  __shared__ __align__(16) bf16 sB[128 * 32];
  const int tid = threadIdx.x;
  const int l = tid & 63, wv = tid >> 6;
  const int wr = wv >> 1, wc = wv & 1;
  const int m0 = blockIdx.y * 128, n0 = blockIdx.x * 128;
  f32x4 acc[4][4];
#pragma unroll
  for (int i = 0; i < 4; ++i)
#pragma unroll
    for (int j = 0; j < 4; ++j) acc[i][j] = (f32x4){0.f, 0.f, 0.f, 0.f};
  const int srow = wv * 16 + (l >> 2);
  const int scol = (l & 3) * 8;
  const bf16* gA = A + (size_t)(m0 + srow) * K + scol;
  const bf16* gB = Bt + (size_t)(n0 + srow) * K + scol;
  bf16* lA = sA + srow * 32 + scol;
  bf16* lB = sB + srow * 32 + scol;
  const int fr = l & 15, fk = (l >> 4) * 8;
  const bf16* rA = sA + (size_t)(wr * 64 + fr) * 32 + fk;
  const bf16* rB = sB + (size_t)(wc * 64 + fr) * 32 + fk;
  for (int k0 = 0; k0 < K; k0 += 32) {
    __syncthreads();
    gload_lds16(gA, lA);
    gload_lds16(gA + (size_t)64 * K, lA + 64 * 32);
    gload_lds16(gB, lB);
    gload_lds16(gB + (size_t)64 * K, lB + 64 * 32);
    gA += 32; gB += 32;
    __syncthreads();
    bf16x8 af[4], bfr[4];
#pragma unroll
    for (int i = 0; i < 4; ++i) af[i] = *(const bf16x8*)(rA + i * 16 * 32);
#pragma unroll
    for (int j = 0; j < 4; ++j) bfr[j] = *(const bf16x8*)(rB + j * 16 * 32);
#pragma unroll
    for (int i = 0; i < 4; ++i)
#pragma unroll
      for (int j = 0; j < 4; ++j)
        acc[i][j] = __builtin_amdgcn_mfma_f32_16x16x32_bf16(af[i], bfr[j], acc[i][j], 0, 0, 0);
  }
  const int cn = n0 + wc * 64 + (l & 15);
  const int rb = m0 + wr * 64 + (l >> 4) * 4;
#pragma unroll
  for (int i = 0; i < 4; ++i)
#pragma unroll
    for (int r = 0; r < 4; ++r) {
      const int m = rb + i * 16 + r;
#pragma unroll
      for (int j = 0; j < 4; ++j) {
        const int n = cn + j * 16;
        float v = acc[i][j][r];
        if (MODE == 0) {
          Dbf[(size_t)m * N + n] = (bf16)v;
        } else if (MODE == 1) {
          float g = (float)Gin[(size_t)m * N + n];
          float s = g / (1.f + expf(-g));
          Dbf[(size_t)m * N + n] = (bf16)(s * v);
        } else if (MODE == 2) {
          outAcc[(size_t)m * N + n] = v;
        } else {
          float w = denseW[(size_t)m * NEXP + expertId];
          outAcc[(size_t)m * N + n] += w * v;
        }
      }
    }
}

extern "C" void kernel_launch(void* const* d_in, const int* in_sizes, int n_in,
                              void* d_out, int out_size, void* d_ws, size_t ws_size,
                              hipStream_t stream) {
  const float* x    = (const float*)d_in[0];
  const float* gate = (const float*)d_in[1];
  const float* sg   = (const float*)d_in[2];
  const float* su   = (const float*)d_in[3];
  const float* sd   = (const float*)d_in[4];
  const float* eg   = (const float*)d_in[5];
  const float* eu   = (const float*)d_in[6];
  const float* ed   = (const float*)d_in[7];
  float* out    = (float*)d_out;
  float* logits = out + (size_t)NTOK * CDIM;

  const size_t MB = 1u << 20;
  const size_t full_need = 226 * MB;

  if (ws_size >= full_need) {
    // ===== sparse top-2 path =====
    char* ws = (char*)d_ws;
    bf16*  xb   = (bf16*)(ws);                    // 16 MB
    bf16*  wTg  = (bf16*)(ws + 16 * MB);          // 9 x 4 MB = 36 MB
    bf16*  wTu  = (bf16*)(ws + 52 * MB);          // 36 MB
    bf16*  wTd  = (bf16*)(ws + 88 * MB);          // 36 MB
    bf16*  act  = (bf16*)(ws + 124 * MB);         // 100 MB
    char*  sm   = ws + 224 * MB;
    int*   list_tok = (int*)(sm);                       // 100 KB
    float* list_w   = (float*)(sm + 128 * 1024);        // 100 KB
    int*   tk_e     = (int*)(sm + 256 * 1024);          // 64 KB
    float* tk_w     = (float*)(sm + 320 * 1024);        // 64 KB
    int*   tile_seg = (int*)(sm + 384 * 1024);          // 800 B
    int*   counts   = (int*)(sm + 388 * 1024);
    int*   fill     = (int*)(sm + 389 * 1024);
    int*   offs     = (int*)(sm + 390 * 1024);

    zero_kernel<<<NTOK * CDIM / (256 * 4), 256, 0, stream>>>(out, counts, fill);
    cast_x_kernel<<<NTOK * CDIM / (256 * 8), 256, 0, stream>>>(x, xb);
    router2_kernel<<<NTOK / 4, 256, 0, stream>>>(x, gate, logits, tk_e, tk_w, counts);
    offsets_kernel<<<1, 256, 0, stream>>>(counts, offs, tile_seg, list_tok, list_w);
    scatter_kernel<<<NTOK / 256, 256, 0, stream>>>(tk_e, tk_w, offs, fill, list_tok, list_w);

    dim3 tgu(HDIM / 64, CDIM / 64, 18);
    dim3 tdd(CDIM / 64, HDIM / 64, 9);
    transpose_gu_kernel<<<tgu, 256, 0, stream>>>(sg, su, eg, eu, (u16*)wTg, (u16*)wTu);
    transpose_d_kernel<<<tdd, 256, 0, stream>>>(sd, ed, (u16*)wTd);

    dim3 ggu(HDIM / 128, MAXTILES);
    gemm_gu<<<ggu, 256, 0, stream>>>(xb, wTg, wTu, tile_seg, list_tok, act);
    dim3 gdn(CDIM / 128, MAXTILES);
    gemm_down<<<gdn, 256, 0, stream>>>(act, wTd, tile_seg, list_tok, list_w, out);
    return;
  }

  // ===== fallback: round-2 dense path (requires ~61 MB) =====
  char* ws = (char*)d_ws;
  bf16*  xb   = (bf16*)(ws);
  bf16*  wTg  = (bf16*)(ws + 16 * MB);
  bf16*  wTu  = (bf16*)(ws + 20 * MB);
  bf16*  wTd  = (bf16*)(ws + 24 * MB);
  bf16*  gbuf = (bf16*)(ws + 28 * MB);
  float* dw   = (float*)(ws + 60 * MB);
  if (ws_size < 60 * MB + (size_t)NTOK * NEXP * sizeof(float)) return;

  cast_x_kernel<<<NTOK * CDIM / (256 * 8), 256, 0, stream>>>(x, xb);
  router_kernel<<<NTOK / 4, 256, 0, stream>>>(x, gate, dw, logits);

  dim3 tg1(HDIM / 64, CDIM / 64);
  dim3 tg2(CDIM / 64, HDIM / 64);
  dim3 g1(HDIM / 128, NTOK / 128);
  dim3 g2(CDIM / 128, NTOK / 128);

  transpose_cast_kernel<<<tg1, 256, 0, stream>>>(sg, (u16*)wTg, CDIM, HDIM);
  transpose_cast_kernel<<<tg1, 256, 0, stream>>>(su, (u16*)wTu, CDIM, HDIM);
  transpose_cast_kernel<<<tg2, 256, 0, stream>>>(sd, (u16*)wTd, HDIM, CDIM);
  gemm_bt<0><<<g1, 256, 0, stream>>>(xb, wTg, CDIM, HDIM, gbuf, nullptr, nullptr, nullptr, 0);
  gemm_bt<1><<<g1, 256, 0, stream>>>(xb, wTu, CDIM, HDIM, gbuf, gbuf, nullptr, nullptr, 0);
  gemm_bt<2><<<g2, 256, 0, stream>>>(gbuf, wTd, HDIM, CDIM, nullptr, nullptr, out, nullptr, 0);

  for (int e = 0; e < NEXP; ++e) {
    const float* egp = eg + (size_t)e * CDIM * HDIM;
    const float* eup = eu + (size_t)e * CDIM * HDIM;
    const float* edp = ed + (size_t)e * HDIM * CDIM;
    transpose_cast_kernel<<<tg1, 256, 0, stream>>>(egp, (u16*)wTg, CDIM, HDIM);
    transpose_cast_kernel<<<tg1, 256, 0, stream>>>(eup, (u16*)wTu, CDIM, HDIM);
    transpose_cast_kernel<<<tg2, 256, 0, stream>>>(edp, (u16*)wTd, HDIM, CDIM);
    gemm_bt<0><<<g1, 256, 0, stream>>>(xb, wTg, CDIM, HDIM, gbuf, nullptr, nullptr, nullptr, 0);
    gemm_bt<1><<<g1, 256, 0, stream>>>(xb, wTu, CDIM, HDIM, gbuf, gbuf, nullptr, nullptr, 0);
    gemm_bt<3><<<g2, 256, 0, stream>>>(gbuf, wTd, HDIM, CDIM, nullptr, nullptr, out, dw, e);
  }
}

// Round 4
// 1166.876 us; speedup vs baseline: 1.6356x; 1.0753x over previous
//
#include <hip/hip_runtime.h>
#include <cstdint>
#include <cstddef>

// Shapes (fixed by the problem)
#define NTOK 8192   // B*T
#define CDIM 1024
#define HDIM 2048
#define NEXP 8
#define NSEG 9        // 8 routed + 1 shared
#define MAXTILES 200  // worst case: ~136 routed tiles + 64 shared
#define MAXROWS (MAXTILES * 128)

typedef __bf16 bf16;
typedef unsigned short u16;
typedef __attribute__((ext_vector_type(8))) __bf16 bf16x8;
typedef __attribute__((ext_vector_type(4))) float f32x4;

__device__ __forceinline__ u16 f2bf(float f) {
  union { u16 u; __bf16 b; } cv;
  cv.b = (__bf16)f;
  return cv.u;
}

// Async global->LDS, 16B per lane. Global address may be per-lane arbitrary;
// only the LDS dest must be wave-uniform base + lane*16 (ours is lane-linear).
__device__ __forceinline__ void gload_lds16(const bf16* g, bf16* l) {
  __builtin_amdgcn_global_load_lds(
      (const __attribute__((address_space(1))) unsigned int*)g,
      (__attribute__((address_space(3))) unsigned int*)l, 16, 0, 0);
}

// ---------------- init control counters ----------------
__global__ __launch_bounds__(64) void init_kernel(int* __restrict__ counts,
                                                  int* __restrict__ fill) {
  if (threadIdx.x < NEXP) {
    counts[threadIdx.x] = 0;
    fill[threadIdx.x] = 0;
  }
}

// ---------------- x: fp32 -> bf16 ----------------
__global__ __launch_bounds__(256) void cast_x_kernel(
    const float* __restrict__ src, bf16* __restrict__ dst) {
  size_t i = ((size_t)blockIdx.x * 256 + threadIdx.x) * 8;
  float4 a = *(const float4*)(src + i);
  float4 b = *(const float4*)(src + i + 4);
  bf16x8 p;
  p[0] = (bf16)a.x; p[1] = (bf16)a.y; p[2] = (bf16)a.z; p[3] = (bf16)a.w;
  p[4] = (bf16)b.x; p[5] = (bf16)b.y; p[6] = (bf16)b.z; p[7] = (bf16)b.w;
  *(bf16x8*)(dst + i) = p;
}

// ---------------- router: logits + top2 + per-expert counts ----------------
__global__ __launch_bounds__(256) void router2_kernel(
    const float* __restrict__ x, const float* __restrict__ gw,
    float* __restrict__ logits_out, int* __restrict__ tk_e,
    float* __restrict__ tk_w, int* __restrict__ counts) {
  int wv = threadIdx.x >> 6, l = threadIdx.x & 63;
  int t = blockIdx.x * 4 + wv;
  const float* xr = x + (size_t)t * CDIM;
  float acc[NEXP];
#pragma unroll
  for (int e = 0; e < NEXP; ++e) acc[e] = 0.f;
  for (int c = l; c < CDIM; c += 64) {
    float xv = xr[c];
    const float* g = gw + (size_t)c * NEXP;
    float4 g0 = *(const float4*)(g);
    float4 g1 = *(const float4*)(g + 4);
    acc[0] += xv * g0.x; acc[1] += xv * g0.y; acc[2] += xv * g0.z; acc[3] += xv * g0.w;
    acc[4] += xv * g1.x; acc[5] += xv * g1.y; acc[6] += xv * g1.z; acc[7] += xv * g1.w;
  }
#pragma unroll
  for (int off = 32; off > 0; off >>= 1) {
#pragma unroll
    for (int e = 0; e < NEXP; ++e) acc[e] += __shfl_xor(acc[e], off, 64);
  }
  int e0 = 0; float l0 = acc[0];
#pragma unroll
  for (int e = 1; e < NEXP; ++e) { if (acc[e] > l0) { l0 = acc[e]; e0 = e; } }
  int e1 = -1; float l1 = -3.4e38f;
#pragma unroll
  for (int e = 0; e < NEXP; ++e) { if (e != e0 && acc[e] > l1) { l1 = acc[e]; e1 = e; } }
  float ex = expf(l1 - l0);
  float w0 = 1.f / (1.f + ex), w1 = ex / (1.f + ex);
  if (l < NEXP) logits_out[(size_t)t * NEXP + l] = acc[l];
  if (l == 0) {
    tk_e[2 * t] = e0; tk_e[2 * t + 1] = e1;
    tk_w[2 * t] = w0; tk_w[2 * t + 1] = w1;
    atomicAdd(&counts[e0], 1);
    atomicAdd(&counts[e1], 1);
  }
}

// ---------------- segment offsets, tile->segment map, pad fill ----------------
__global__ __launch_bounds__(256) void offsets_kernel(
    const int* __restrict__ counts, int* __restrict__ offs_g,
    int* __restrict__ tile_seg, int* __restrict__ list_tok) {
  __shared__ int off[NSEG], pad[NSEG], cnt[NSEG], ntot;
  int tid = threadIdx.x;
  if (tid == 0) {
    int tot = 0;
    for (int e = 0; e < NSEG; ++e) {
      int c = (e < NEXP) ? counts[e] : NTOK;
      cnt[e] = c; off[e] = tot;
      int p = (c + 127) & ~127;
      pad[e] = p; tot += p;
    }
    ntot = tot;
  }
  __syncthreads();
  if (tid < NSEG) offs_g[tid] = off[tid];
  for (int gt = tid; gt < MAXTILES; gt += 256) {
    int row = gt * 128, seg = -1;
    if (row < ntot) {
      for (int e = 0; e < NSEG; ++e)
        if (row >= off[e] && row < off[e] + pad[e]) { seg = e; break; }
    }
    tile_seg[gt] = seg;
  }
  for (int e = 0; e < NSEG; ++e)
    for (int i = off[e] + cnt[e] + tid; i < off[e] + pad[e]; i += 256)
      list_tok[i] = 0;
}

// ---------------- scatter tokens into compact lists + inverse map ----------------
__global__ __launch_bounds__(256) void scatter_kernel(
    const int* __restrict__ tk_e, const int* __restrict__ offs,
    int* __restrict__ fill, int* __restrict__ list_tok,
    int* __restrict__ inv) {
  int t = blockIdx.x * 256 + threadIdx.x;
  int e0 = tk_e[2 * t], e1 = tk_e[2 * t + 1];
  int p0 = atomicAdd(&fill[e0], 1);
  int i0 = offs[e0] + p0;
  list_tok[i0] = t; inv[2 * t] = i0;
  int p1 = atomicAdd(&fill[e1], 1);
  int i1 = offs[e1] + p1;
  list_tok[i1] = t; inv[2 * t + 1] = i1;
  list_tok[offs[NEXP] + t] = t;  // shared segment: identity
}

// ---------------- transpose+cast body: fp32 RxC -> bf16 CxR ----------------
__device__ __forceinline__ void transpose_body(const float* __restrict__ src,
                                               u16* __restrict__ dst, int R, int C) {
  __shared__ u16 tile[64][65];
  int r0 = blockIdx.y * 64, c0 = blockIdx.x * 64;
  int tr = threadIdx.x >> 2;
  int tc = (threadIdx.x & 3) * 16;
  const float* s = src + (size_t)(r0 + tr) * C + c0 + tc;
  float4 f[4];
#pragma unroll
  for (int q = 0; q < 4; ++q) f[q] = *(const float4*)(s + q * 4);
#pragma unroll
  for (int q = 0; q < 4; ++q) {
    tile[tr][tc + q * 4 + 0] = f2bf(f[q].x);
    tile[tr][tc + q * 4 + 1] = f2bf(f[q].y);
    tile[tr][tc + q * 4 + 2] = f2bf(f[q].z);
    tile[tr][tc + q * 4 + 3] = f2bf(f[q].w);
  }
  __syncthreads();
  union { uint4 v[2]; u16 e[16]; } u;
#pragma unroll
  for (int j = 0; j < 16; ++j) u.e[j] = tile[tc + j][tr];
  u16* d = dst + (size_t)(c0 + tr) * R + r0 + tc;
  *(uint4*)d = u.v[0];
  *(uint4*)(d + 8) = u.v[1];
}

__global__ __launch_bounds__(256) void transpose_cast_kernel(
    const float* __restrict__ src, u16* __restrict__ dst, int R, int C) {
  transpose_body(src, dst, R, C);
}

// gate/up weights: (C,H) -> (H,C). z: 0=sg,1=su, 2..9=eg[e], 10..17=eu[e]
__global__ __launch_bounds__(256) void transpose_gu_kernel(
    const float* __restrict__ sg, const float* __restrict__ su,
    const float* __restrict__ eg, const float* __restrict__ eu,
    u16* __restrict__ wTg, u16* __restrict__ wTu) {
  const size_t slot = (size_t)HDIM * CDIM;
  int z = blockIdx.z;
  const float* src; u16* dst;
  if (z == 0)       { src = sg;                 dst = wTg + 8 * slot; }
  else if (z == 1)  { src = su;                 dst = wTu + 8 * slot; }
  else if (z < 10)  { src = eg + (z - 2) * slot;  dst = wTg + (z - 2) * slot; }
  else              { src = eu + (z - 10) * slot; dst = wTu + (z - 10) * slot; }
  transpose_body(src, dst, CDIM, HDIM);
}

// down weights: (H,C) -> (C,H). z: 0=sd, 1..8=ed[e]
__global__ __launch_bounds__(256) void transpose_d_kernel(
    const float* __restrict__ sd, const float* __restrict__ ed,
    u16* __restrict__ wTd) {
  const size_t slot = (size_t)HDIM * CDIM;
  int z = blockIdx.z;
  const float* src; u16* dst;
  if (z == 0) { src = sd;                 dst = wTd + 8 * slot; }
  else        { src = ed + (z - 1) * slot; dst = wTd + (z - 1) * slot; }
  transpose_body(src, dst, HDIM, CDIM);
}

// ---------------- fused gate+up gather-GEMM with silu epilogue ----------------
__global__ __launch_bounds__(256) void gemm_gu(
    const bf16* __restrict__ xb, const bf16* __restrict__ wTg,
    const bf16* __restrict__ wTu, const int* __restrict__ tile_seg,
    const int* __restrict__ list_tok, bf16* __restrict__ act) {
  __shared__ __align__(16) bf16 sA[128 * 32];
  __shared__ __align__(16) bf16 sBg[128 * 32];
  __shared__ __align__(16) bf16 sBu[128 * 32];
  __shared__ int tokLds[128];
  const int seg = tile_seg[blockIdx.y];
  if (seg < 0) return;
  const int tid = threadIdx.x, l = tid & 63, wv = tid >> 6;
  const int wr = wv >> 1, wc = wv & 1;
  const int n0 = blockIdx.x * 128;
  const size_t rowbase = (size_t)blockIdx.y * 128;
  if (tid < 128) tokLds[tid] = list_tok[rowbase + tid];
  __syncthreads();

  f32x4 accG[4][4], accU[4][4];
#pragma unroll
  for (int i = 0; i < 4; ++i)
#pragma unroll
    for (int j = 0; j < 4; ++j) {
      accG[i][j] = (f32x4){0.f, 0.f, 0.f, 0.f};
      accU[i][j] = (f32x4){0.f, 0.f, 0.f, 0.f};
    }

  const int srow = wv * 16 + (l >> 2);
  const int scol = (l & 3) * 8;
  const bf16* gA  = xb + (size_t)tokLds[srow] * CDIM + scol;
  const bf16* gA2 = xb + (size_t)tokLds[srow + 64] * CDIM + scol;
  const size_t wslot = (size_t)seg * HDIM * CDIM;
  const bf16* gBg = wTg + wslot + (size_t)(n0 + srow) * CDIM + scol;
  const bf16* gBu = wTu + wslot + (size_t)(n0 + srow) * CDIM + scol;
  bf16* lA  = sA  + srow * 32 + scol;
  bf16* lBg = sBg + srow * 32 + scol;
  bf16* lBu = sBu + srow * 32 + scol;

  const int fr = l & 15, fk = (l >> 4) * 8;
  const bf16* rA  = sA  + (size_t)(wr * 64 + fr) * 32 + fk;
  const bf16* rBg = sBg + (size_t)(wc * 64 + fr) * 32 + fk;
  const bf16* rBu = sBu + (size_t)(wc * 64 + fr) * 32 + fk;

  for (int k0 = 0; k0 < CDIM; k0 += 32) {
    __syncthreads();
    gload_lds16(gA, lA);
    gload_lds16(gA2, lA + 64 * 32);
    gload_lds16(gBg, lBg);
    gload_lds16(gBg + (size_t)64 * CDIM, lBg + 64 * 32);
    gload_lds16(gBu, lBu);
    gload_lds16(gBu + (size_t)64 * CDIM, lBu + 64 * 32);
    gA += 32; gA2 += 32; gBg += 32; gBu += 32;
    __syncthreads();
    bf16x8 af[4], bg[4], bu[4];
#pragma unroll
    for (int i = 0; i < 4; ++i) af[i] = *(const bf16x8*)(rA + i * 16 * 32);
#pragma unroll
    for (int j = 0; j < 4; ++j) bg[j] = *(const bf16x8*)(rBg + j * 16 * 32);
#pragma unroll
    for (int j = 0; j < 4; ++j) bu[j] = *(const bf16x8*)(rBu + j * 16 * 32);
#pragma unroll
    for (int i = 0; i < 4; ++i)
#pragma unroll
      for (int j = 0; j < 4; ++j) {
        accG[i][j] = __builtin_amdgcn_mfma_f32_16x16x32_bf16(af[i], bg[j], accG[i][j], 0, 0, 0);
        accU[i][j] = __builtin_amdgcn_mfma_f32_16x16x32_bf16(af[i], bu[j], accU[i][j], 0, 0, 0);
      }
  }

  const int cn = n0 + wc * 64 + (l & 15);
  const int rb = wr * 64 + (l >> 4) * 4;
#pragma unroll
  for (int i = 0; i < 4; ++i)
#pragma unroll
    for (int r = 0; r < 4; ++r) {
      const size_t row = rowbase + rb + i * 16 + r;
#pragma unroll
      for (int j = 0; j < 4; ++j) {
        float g = accG[i][j][r], u = accU[i][j][r];
        float s = g / (1.f + expf(-g));
        act[row * HDIM + cn + j * 16] = (bf16)(s * u);
      }
    }
}

// ---------------- down-proj GEMM: plain bf16 row store (no atomics) ----------------
__global__ __launch_bounds__(256) void gemm_down(
    const bf16* __restrict__ act, const bf16* __restrict__ wTd,
    const int* __restrict__ tile_seg, bf16* __restrict__ dbuf) {
  __shared__ __align__(16) bf16 sA[128 * 32];
  __shared__ __align__(16) bf16 sB[128 * 32];
  const int seg = tile_seg[blockIdx.y];
  if (seg < 0) return;
  const int tid = threadIdx.x, l = tid & 63, wv = tid >> 6;
  const int wr = wv >> 1, wc = wv & 1;
  const int n0 = blockIdx.x * 128;
  const size_t rowbase = (size_t)blockIdx.y * 128;

  f32x4 acc[4][4];
#pragma unroll
  for (int i = 0; i < 4; ++i)
#pragma unroll
    for (int j = 0; j < 4; ++j) acc[i][j] = (f32x4){0.f, 0.f, 0.f, 0.f};

  const int srow = wv * 16 + (l >> 2);
  const int scol = (l & 3) * 8;
  const bf16* gA = act + (rowbase + srow) * HDIM + scol;
  const bf16* gB = wTd + (size_t)seg * CDIM * HDIM + (size_t)(n0 + srow) * HDIM + scol;
  bf16* lA = sA + srow * 32 + scol;
  bf16* lB = sB + srow * 32 + scol;

  const int fr = l & 15, fk = (l >> 4) * 8;
  const bf16* rA = sA + (size_t)(wr * 64 + fr) * 32 + fk;
  const bf16* rB = sB + (size_t)(wc * 64 + fr) * 32 + fk;

  for (int k0 = 0; k0 < HDIM; k0 += 32) {
    __syncthreads();
    gload_lds16(gA, lA);
    gload_lds16(gA + (size_t)64 * HDIM, lA + 64 * 32);
    gload_lds16(gB, lB);
    gload_lds16(gB + (size_t)64 * HDIM, lB + 64 * 32);
    gA += 32; gB += 32;
    __syncthreads();
    bf16x8 af[4], bf[4];
#pragma unroll
    for (int i = 0; i < 4; ++i) af[i] = *(const bf16x8*)(rA + i * 16 * 32);
#pragma unroll
    for (int j = 0; j < 4; ++j) bf[j] = *(const bf16x8*)(rB + j * 16 * 32);
#pragma unroll
    for (int i = 0; i < 4; ++i)
#pragma unroll
      for (int j = 0; j < 4; ++j)
        acc[i][j] = __builtin_amdgcn_mfma_f32_16x16x32_bf16(af[i], bf[j], acc[i][j], 0, 0, 0);
  }

  const int cn = n0 + wc * 64 + (l & 15);
  const int rb = wr * 64 + (l >> 4) * 4;
#pragma unroll
  for (int i = 0; i < 4; ++i)
#pragma unroll
    for (int r = 0; r < 4; ++r) {
      const size_t row = rowbase + rb + i * 16 + r;
#pragma unroll
      for (int j = 0; j < 4; ++j)
        dbuf[row * CDIM + cn + j * 16] = (bf16)acc[i][j][r];
    }
}

// ---------------- combine: out[t] = shared + w0*d0 + w1*d1 ----------------
__global__ __launch_bounds__(128) void combine_kernel(
    const bf16* __restrict__ dbuf, const int* __restrict__ offs,
    const int* __restrict__ inv, const float* __restrict__ tk_w,
    float* __restrict__ out) {
  const int t = blockIdx.x;
  const int c = threadIdx.x * 8;
  const int rsh = offs[NEXP] + t;
  const int i0 = inv[2 * t], i1 = inv[2 * t + 1];
  const float w0 = tk_w[2 * t], w1 = tk_w[2 * t + 1];
  bf16x8 a = *(const bf16x8*)(dbuf + (size_t)rsh * CDIM + c);
  bf16x8 b = *(const bf16x8*)(dbuf + (size_t)i0 * CDIM + c);
  bf16x8 d = *(const bf16x8*)(dbuf + (size_t)i1 * CDIM + c);
  float* op = out + (size_t)t * CDIM + c;
#pragma unroll
  for (int j = 0; j < 8; ++j)
    op[j] = (float)a[j] + w0 * (float)b[j] + w1 * (float)d[j];
}

// ================= FALLBACK (round-2 dense path) =================
__global__ __launch_bounds__(256) void router_kernel(
    const float* __restrict__ x, const float* __restrict__ gw,
    float* __restrict__ dense_w, float* __restrict__ logits_out) {
  int wv = threadIdx.x >> 6, l = threadIdx.x & 63;
  int t = blockIdx.x * 4 + wv;
  const float* xr = x + (size_t)t * CDIM;
  float acc[NEXP];
#pragma unroll
  for (int e = 0; e < NEXP; ++e) acc[e] = 0.f;
  for (int c = l; c < CDIM; c += 64) {
    float xv = xr[c];
    const float* g = gw + (size_t)c * NEXP;
    float4 g0 = *(const float4*)(g);
    float4 g1 = *(const float4*)(g + 4);
    acc[0] += xv * g0.x; acc[1] += xv * g0.y; acc[2] += xv * g0.z; acc[3] += xv * g0.w;
    acc[4] += xv * g1.x; acc[5] += xv * g1.y; acc[6] += xv * g1.z; acc[7] += xv * g1.w;
  }
#pragma unroll
  for (int off = 32; off > 0; off >>= 1) {
#pragma unroll
    for (int e = 0; e < NEXP; ++e) acc[e] += __shfl_xor(acc[e], off, 64);
  }
  int e0 = 0; float l0 = acc[0];
#pragma unroll
  for (int e = 1; e < NEXP; ++e) { if (acc[e] > l0) { l0 = acc[e]; e0 = e; } }
  int e1 = -1; float l1 = -3.4e38f;
#pragma unroll
  for (int e = 0; e < NEXP; ++e) { if (e != e0 && acc[e] > l1) { l1 = acc[e]; e1 = e; } }
  float ex = expf(l1 - l0);
  float w0 = 1.f / (1.f + ex), w1 = ex / (1.f + ex);
  if (l < NEXP) {
    dense_w[(size_t)t * NEXP + l] = (l == e0) ? w0 : ((l == e1) ? w1 : 0.f);
    logits_out[(size_t)t * NEXP + l] = acc[l];
  }
}

template <int MODE>
__global__ __launch_bounds__(256) void gemm_bt(
    const bf16* __restrict__ A, const bf16* __restrict__ Bt,
    int K, int N,
    bf16* __restrict__ Dbf, const bf16* __restrict__ Gin,
    float* __restrict__ outAcc, const float* __restrict__ denseW, int expertId) {
  __shared__ __align__(16) bf16 sA[128 * 32];
  __shared__ __align__(16) bf16 sB[128 * 32];
  const int tid = threadIdx.x;
  const int l = tid & 63, wv = tid >> 6;
  const int wr = wv >> 1, wc = wv & 1;
  const int m0 = blockIdx.y * 128, n0 = blockIdx.x * 128;
  f32x4 acc[4][4];
#pragma unroll
  for (int i = 0; i < 4; ++i)
#pragma unroll
    for (int j = 0; j < 4; ++j) acc[i][j] = (f32x4){0.f, 0.f, 0.f, 0.f};
  const int srow = wv * 16 + (l >> 2);
  const int scol = (l & 3) * 8;
  const bf16* gA = A + (size_t)(m0 + srow) * K + scol;
  const bf16* gB = Bt + (size_t)(n0 + srow) * K + scol;
  bf16* lA = sA + srow * 32 + scol;
  bf16* lB = sB + srow * 32 + scol;
  const int fr = l & 15, fk = (l >> 4) * 8;
  const bf16* rA = sA + (size_t)(wr * 64 + fr) * 32 + fk;
  const bf16* rB = sB + (size_t)(wc * 64 + fr) * 32 + fk;
  for (int k0 = 0; k0 < K; k0 += 32) {
    __syncthreads();
    gload_lds16(gA, lA);
    gload_lds16(gA + (size_t)64 * K, lA + 64 * 32);
    gload_lds16(gB, lB);
    gload_lds16(gB + (size_t)64 * K, lB + 64 * 32);
    gA += 32; gB += 32;
    __syncthreads();
    bf16x8 af[4], bfr[4];
#pragma unroll
    for (int i = 0; i < 4; ++i) af[i] = *(const bf16x8*)(rA + i * 16 * 32);
#pragma unroll
    for (int j = 0; j < 4; ++j) bfr[j] = *(const bf16x8*)(rB + j * 16 * 32);
#pragma unroll
    for (int i = 0; i < 4; ++i)
#pragma unroll
      for (int j = 0; j < 4; ++j)
        acc[i][j] = __builtin_amdgcn_mfma_f32_16x16x32_bf16(af[i], bfr[j], acc[i][j], 0, 0, 0);
  }
  const int cn = n0 + wc * 64 + (l & 15);
  const int rb = m0 + wr * 64 + (l >> 4) * 4;
#pragma unroll
  for (int i = 0; i < 4; ++i)
#pragma unroll
    for (int r = 0; r < 4; ++r) {
      const int m = rb + i * 16 + r;
#pragma unroll
      for (int j = 0; j < 4; ++j) {
        const int n = cn + j * 16;
        float v = acc[i][j][r];
        if (MODE == 0) {
          Dbf[(size_t)m * N + n] = (bf16)v;
        } else if (MODE == 1) {
          float g = (float)Gin[(size_t)m * N + n];
          float s = g / (1.f + expf(-g));
          Dbf[(size_t)m * N + n] = (bf16)(s * v);
        } else if (MODE == 2) {
          outAcc[(size_t)m * N + n] = v;
        } else {
          float w = denseW[(size_t)m * NEXP + expertId];
          outAcc[(size_t)m * N + n] += w * v;
        }
      }
    }
}

extern "C" void kernel_launch(void* const* d_in, const int* in_sizes, int n_in,
                              void* d_out, int out_size, void* d_ws, size_t ws_size,
                              hipStream_t stream) {
  const float* x    = (const float*)d_in[0];
  const float* gate = (const float*)d_in[1];
  const float* sg   = (const float*)d_in[2];
  const float* su   = (const float*)d_in[3];
  const float* sd   = (const float*)d_in[4];
  const float* eg   = (const float*)d_in[5];
  const float* eu   = (const float*)d_in[6];
  const float* ed   = (const float*)d_in[7];
  float* out    = (float*)d_out;
  float* logits = out + (size_t)NTOK * CDIM;

  const size_t MB = 1u << 20;
  const size_t full_need = 226 * MB;

  if (ws_size >= full_need) {
    // ===== sparse top-2 path =====
    char* ws = (char*)d_ws;
    bf16*  xb   = (bf16*)(ws);                    // 16 MB   (dead after gemm_gu)
    bf16*  wTg  = (bf16*)(ws + 16 * MB);          // 36 MB   (dead after gemm_gu)
    bf16*  wTu  = (bf16*)(ws + 52 * MB);          // 36 MB   (dead after gemm_gu)
    bf16*  wTd  = (bf16*)(ws + 88 * MB);          // 36 MB
    bf16*  act  = (bf16*)(ws + 124 * MB);         // 100 MB
    bf16*  dbuf = (bf16*)(ws);                    // 52.4 MB, aliases xb+wTg (safe: written only by gemm_down)
    char*  sm   = ws + 224 * MB;
    int*   list_tok = (int*)(sm);                       // 100 KB
    int*   inv      = (int*)(sm + 128 * 1024);          // 64 KB
    int*   tk_e     = (int*)(sm + 256 * 1024);          // 64 KB
    float* tk_w     = (float*)(sm + 320 * 1024);        // 64 KB
    int*   tile_seg = (int*)(sm + 384 * 1024);          // 800 B
    int*   counts   = (int*)(sm + 388 * 1024);
    int*   fill     = (int*)(sm + 389 * 1024);
    int*   offs     = (int*)(sm + 390 * 1024);

    init_kernel<<<1, 64, 0, stream>>>(counts, fill);
    cast_x_kernel<<<NTOK * CDIM / (256 * 8), 256, 0, stream>>>(x, xb);
    router2_kernel<<<NTOK / 4, 256, 0, stream>>>(x, gate, logits, tk_e, tk_w, counts);
    offsets_kernel<<<1, 256, 0, stream>>>(counts, offs, tile_seg, list_tok);
    scatter_kernel<<<NTOK / 256, 256, 0, stream>>>(tk_e, offs, fill, list_tok, inv);

    dim3 tgu(HDIM / 64, CDIM / 64, 18);
    dim3 tdd(CDIM / 64, HDIM / 64, 9);
    transpose_gu_kernel<<<tgu, 256, 0, stream>>>(sg, su, eg, eu, (u16*)wTg, (u16*)wTu);
    transpose_d_kernel<<<tdd, 256, 0, stream>>>(sd, ed, (u16*)wTd);

    dim3 ggu(HDIM / 128, MAXTILES);
    gemm_gu<<<ggu, 256, 0, stream>>>(xb, wTg, wTu, tile_seg, list_tok, act);
    dim3 gdn(CDIM / 128, MAXTILES);
    gemm_down<<<gdn, 256, 0, stream>>>(act, wTd, tile_seg, dbuf);
    combine_kernel<<<NTOK, 128, 0, stream>>>(dbuf, offs, inv, tk_w, out);
    return;
  }

  // ===== fallback: round-2 dense path (requires ~61 MB) =====
  char* ws = (char*)d_ws;
  bf16*  xb   = (bf16*)(ws);
  bf16*  wTgf = (bf16*)(ws + 16 * MB);
  bf16*  wTuf = (bf16*)(ws + 20 * MB);
  bf16*  wTdf = (bf16*)(ws + 24 * MB);
  bf16*  gbuf = (bf16*)(ws + 28 * MB);
  float* dw   = (float*)(ws + 60 * MB);
  if (ws_size < 60 * MB + (size_t)NTOK * NEXP * sizeof(float)) return;

  cast_x_kernel<<<NTOK * CDIM / (256 * 8), 256, 0, stream>>>(x, xb);
  router_kernel<<<NTOK / 4, 256, 0, stream>>>(x, gate, dw, logits);

  dim3 tg1(HDIM / 64, CDIM / 64);
  dim3 tg2(CDIM / 64, HDIM / 64);
  dim3 g1(HDIM / 128, NTOK / 128);
  dim3 g2(CDIM / 128, NTOK / 128);

  transpose_cast_kernel<<<tg1, 256, 0, stream>>>(sg, (u16*)wTgf, CDIM, HDIM);
  transpose_cast_kernel<<<tg1, 256, 0, stream>>>(su, (u16*)wTuf, CDIM, HDIM);
  transpose_cast_kernel<<<tg2, 256, 0, stream>>>(sd, (u16*)wTdf, HDIM, CDIM);
  gemm_bt<0><<<g1, 256, 0, stream>>>(xb, wTgf, CDIM, HDIM, gbuf, nullptr, nullptr, nullptr, 0);
  gemm_bt<1><<<g1, 256, 0, stream>>>(xb, wTuf, CDIM, HDIM, gbuf, gbuf, nullptr, nullptr, 0);
  gemm_bt<2><<<g2, 256, 0, stream>>>(gbuf, wTdf, HDIM, CDIM, nullptr, nullptr, out, nullptr, 0);

  for (int e = 0; e < NEXP; ++e) {
    const float* egp = eg + (size_t)e * CDIM * HDIM;
    const float* eup = eu + (size_t)e * CDIM * HDIM;
    const float* edp = ed + (size_t)e * HDIM * CDIM;
    transpose_cast_kernel<<<tg1, 256, 0, stream>>>(egp, (u16*)wTgf, CDIM, HDIM);
    transpose_cast_kernel<<<tg1, 256, 0, stream>>>(eup, (u16*)wTuf, CDIM, HDIM);
    transpose_cast_kernel<<<tg2, 256, 0, stream>>>(edp, (u16*)wTdf, HDIM, CDIM);
    gemm_bt<0><<<g1, 256, 0, stream>>>(xb, wTgf, CDIM, HDIM, gbuf, nullptr, nullptr, nullptr, 0);
    gemm_bt<1><<<g1, 256, 0, stream>>>(xb, wTuf, CDIM, HDIM, gbuf, gbuf, nullptr, nullptr, 0);
    gemm_bt<3><<<g2, 256, 0, stream>>>(gbuf, wTdf, HDIM, CDIM, nullptr, nullptr, out, dw, e);
  }
}